// Round 22
// baseline (384.252 us; speedup 1.0000x reference)
//
#include <hip/hip_runtime.h>
#include <hip/hip_bf16.h>
#include <hip/hip_fp16.h>
#include <math.h>

#define S    2048
#define HQ   16
#define D    128
#define HI   16
#define DI   128
#define KSEL 512
#define OPW  132   // opart row stride (floats)

typedef __attribute__((ext_vector_type(8))) short short8;
typedef __attribute__((ext_vector_type(4))) float f32x4;
typedef __attribute__((ext_vector_type(2))) float f32x2;
typedef __attribute__((ext_vector_type(2))) _Float16 h2v;

// ---------------- reductions (wave = 64) ----------------
__device__ __forceinline__ float waveReduceSum(float v) {
#pragma unroll
    for (int o = 32; o > 0; o >>= 1) v += __shfl_down(v, o);
    return v;
}
__device__ __forceinline__ float waveReduceMax(float v) {
#pragma unroll
    for (int o = 32; o > 0; o >>= 1) v = fmaxf(v, __shfl_down(v, o));
    return v;
}
__device__ __forceinline__ float blockReduceSum(float v, float* tmp) {
    int wid = threadIdx.x >> 6, lane = threadIdx.x & 63;
    v = waveReduceSum(v);
    __syncthreads();
    if (lane == 0) tmp[wid] = v;
    __syncthreads();
    return tmp[0] + tmp[1] + tmp[2] + tmp[3];
}
__device__ __forceinline__ float blockReduceMax(float v, float* tmp) {
    int wid = threadIdx.x >> 6, lane = threadIdx.x & 63;
    v = waveReduceMax(v);
    __syncthreads();
    if (lane == 0) tmp[wid] = v;
    __syncthreads();
    return fmaxf(fmaxf(tmp[0], tmp[1]), fmaxf(tmp[2], tmp[3]));
}

__device__ __forceinline__ unsigned short f2bf(float f) {  // RNE
    unsigned int u = __float_as_uint(f);
    return (unsigned short)((u + 0x7FFFu + ((u >> 16) & 1u)) >> 16);
}
__device__ __forceinline__ float bf2f(unsigned short h) {
    return __uint_as_float(((unsigned int)h) << 16);
}
__device__ __forceinline__ float fdot2u(unsigned int a, unsigned int b, float c) {
    return __builtin_amdgcn_fdot2(__builtin_bit_cast(h2v, a),
                                  __builtin_bit_cast(h2v, b), c, false);
}
__device__ __forceinline__ f32x2 f2shfl_xor(f32x2 v, int m) {
    f32x2 r;
    r.x = __shfl_xor(v.x, m);
    r.y = __shfl_xor(v.y, m);
    return r;
}
__device__ __forceinline__ void split4(const float* in, unsigned short* hi,
                                       unsigned short* lo, int i) {
    float4 x = ((const float4*)in)[i];
    ushort4 h4, l4;
    h4.x = f2bf(x.x); l4.x = f2bf(x.x - bf2f(h4.x));
    h4.y = f2bf(x.y); l4.y = f2bf(x.y - bf2f(h4.y));
    h4.z = f2bf(x.z); l4.z = f2bf(x.z - bf2f(h4.z));
    h4.w = f2bf(x.w); l4.w = f2bf(x.w - bf2f(h4.w));
    ((ushort4*)hi)[i] = h4;
    ((ushort4*)lo)[i] = l4;
}

// ---------------- fused prep: K->f16, V->fp8, qi/ki bf16-split, zero aacc ----------------
__global__ __launch_bounds__(256) void prep_all(
    const float* __restrict__ kin, const float* __restrict__ vin,
    unsigned short* __restrict__ Kh, unsigned int* __restrict__ Vq,
    const float* __restrict__ qi, unsigned short* __restrict__ qih,
    unsigned short* __restrict__ qil,
    const float* __restrict__ ki, unsigned short* __restrict__ kih,
    unsigned short* __restrict__ kil,
    float* __restrict__ aacc_g,
    int n4kv, int n4q, int n4k, int n4acc) {
    const int stride = gridDim.x * 256;
    const int t0 = blockIdx.x * 256 + threadIdx.x;
    for (int i = t0; i < n4kv; i += stride) {
        float4 x = ((const float4*)kin)[i];
        uint2 r;
        r.x = __builtin_bit_cast(unsigned int, __floats2half2_rn(x.x, x.y));
        r.y = __builtin_bit_cast(unsigned int, __floats2half2_rn(x.z, x.w));
        ((uint2*)Kh)[i] = r;
        float4 y = ((const float4*)vin)[i];
        int u = 0;
        u = __builtin_amdgcn_cvt_pk_fp8_f32(y.x, y.y, u, false);
        u = __builtin_amdgcn_cvt_pk_fp8_f32(y.z, y.w, u, true);
        Vq[i] = (unsigned int)u;
    }
    for (int i = t0; i < n4q; i += stride) split4(qi, qih, qil, i);
    for (int i = t0; i < n4k; i += stride) split4(ki, kih, kil, i);
    float4 z = make_float4(0.f, 0.f, 0.f, 0.f);
    for (int i = t0; i < n4acc; i += stride) ((float4*)aacc_g)[i] = z;
}

// ---------------- shared device radix top-k (scores in LDS, >= 0) ----------------
__device__ void topk_from_scores(const float* scores, int ncand, int K, int q,
                                 int* __restrict__ topk_idx, float* __restrict__ topk_score,
                                 unsigned int* bins, unsigned int* sh_u, unsigned int* cnt_p) {
    const int tid = threadIdx.x;
    if (ncand <= K) {
        for (int j = tid; j < KSEL; j += 256) {
            if (j < ncand) {
                topk_idx[q * KSEL + j]   = j;
                topk_score[q * KSEL + j] = scores[j];
            } else {
                topk_idx[q * KSEL + j]   = -1;
                topk_score[q * KSEL + j] = -INFINITY;
            }
        }
        __syncthreads();
        return;
    }

    unsigned int prefix = 0;
    int need = K;
    for (int pass = 0; pass < 4; ++pass) {
        const int shift = 24 - pass * 8;
        for (int b = tid; b < 256; b += 256) bins[b] = 0;
        __syncthreads();
        const unsigned int himask = (pass == 0) ? 0u : (0xFFFFFFFFu << (shift + 8));
        for (int k = tid; k < ncand; k += 256) {
            unsigned int u = __float_as_uint(scores[k]);
            if ((u & himask) == prefix) atomicAdd(&bins[(u >> shift) & 0xFF], 1u);
        }
        __syncthreads();
        if (tid < 64) {
            const int l = tid;
            unsigned int b0 = bins[4 * l], b1 = bins[4 * l + 1],
                         b2 = bins[4 * l + 2], b3 = bins[4 * l + 3];
            unsigned int s3 = b3, s2 = b2 + s3, s1 = b1 + s2, s0 = b0 + s1;
            unsigned int acc = s0;
#pragma unroll
            for (int off = 1; off < 64; off <<= 1) {
                unsigned int t = __shfl_down(acc, off);
                if (l + off < 64) acc += t;
            }
            const unsigned int above = acc - s0;
            const unsigned int S0 = s0 + above, S1 = s1 + above,
                               S2 = s2 + above, S3 = s3 + above;
            const unsigned int nd = (unsigned int)need;
            if (4 * l + 0 >= 1 && S0 >= nd && S1 < nd) {
                sh_u[0] = prefix | ((unsigned int)(4 * l + 0) << shift);
                sh_u[1] = nd - S1;
            }
            if (S1 >= nd && S2 < nd) {
                sh_u[0] = prefix | ((unsigned int)(4 * l + 1) << shift);
                sh_u[1] = nd - S2;
            }
            if (S2 >= nd && S3 < nd) {
                sh_u[0] = prefix | ((unsigned int)(4 * l + 2) << shift);
                sh_u[1] = nd - S3;
            }
            if (S3 >= nd && above < nd) {
                sh_u[0] = prefix | ((unsigned int)(4 * l + 3) << shift);
                sh_u[1] = nd - above;
            }
            if (l == 0 && S1 < nd) {
                sh_u[0] = prefix;
                sh_u[1] = nd - S1;
            }
        }
        __syncthreads();
        prefix = sh_u[0];
        need   = (int)sh_u[1];
        __syncthreads();
    }
    const unsigned int ueqT = prefix;
    const int count_eq = (int)bins[ueqT & 0xFF];
    __syncthreads();
    if (tid == 0) *cnt_p = 0;
    __syncthreads();

    for (int k = tid; k < ncand; k += 256) {
        unsigned int u = __float_as_uint(scores[k]);
        if (u > ueqT) {
            unsigned int slot = atomicAdd(cnt_p, 1u);
            topk_idx[q * KSEL + slot]   = k;
            topk_score[q * KSEL + slot] = scores[k];
        }
    }
    __syncthreads();
    if (count_eq == need) {
        for (int k = tid; k < ncand; k += 256) {
            if (__float_as_uint(scores[k]) == ueqT) {
                unsigned int slot = atomicAdd(cnt_p, 1u);
                topk_idx[q * KSEL + slot]   = k;
                topk_score[q * KSEL + slot] = __uint_as_float(ueqT);
            }
        }
    } else if (tid == 0) {
        int emitted = 0;
        for (int k = 0; k < ncand && emitted < need; ++k) {
            if (__float_as_uint(scores[k]) == ueqT) {
                unsigned int slot = atomicAdd(cnt_p, 1u);
                topk_idx[q * KSEL + slot]   = k;
                topk_score[q * KSEL + slot] = __uint_as_float(ueqT);
                emitted++;
            }
        }
    }
    __syncthreads();
}

// ---------------- Kernel A (MFMA): indexer via 2-term split-bf16 MFMA + radix topk ----------------
// 2-term split: Ah*(Bh+Bl); dropped Al*Bh term ~2^-9 relative (score err ~0.05
// vs spread ~+-40 -> only boundary keys with smallest weights can flip).
__global__ __launch_bounds__(256) void indexer_mfma(
    const unsigned short* __restrict__ qih, const unsigned short* __restrict__ qil,
    const unsigned short* __restrict__ kih, const unsigned short* __restrict__ kil,
    const float* __restrict__ w,
    const int* __restrict__ topk_p, const int* __restrict__ endpos_p,
    int* __restrict__ topk_idx, float* __restrict__ topk_score)
{
    const int tid  = threadIdx.x;
    const int wv   = tid >> 6;
    const int lane = tid & 63;
    int K = min(topk_p[0], endpos_p[0]);
    K = min(K, KSEL);

    __shared__ float scores[S];
    __shared__ float w_sh[HI];
    __shared__ unsigned int bins[256];
    __shared__ unsigned int sh_u[3];
    __shared__ unsigned int cnt;

    const int mrow = lane & 15;
    const int kgrp = lane >> 4;

    const int b = blockIdx.x;
    for (int qq = 0; qq < 2; ++qq) {
        const int q = qq ? (S - 1 - b) : b;
        if (tid < HI) w_sh[tid] = w[q * HI + tid];
        __syncthreads();

        short8 Ah[4];
        {
            const unsigned short* bh = qih + ((size_t)q * HI + mrow) * DI + kgrp * 8;
#pragma unroll
            for (int dc = 0; dc < 4; dc++)
                Ah[dc] = *(const short8*)(bh + dc * 32);
        }
        float wreg[4];
#pragma unroll
        for (int e = 0; e < 4; e++) wreg[e] = w_sh[4 * kgrp + e];

        const int nkt = (q >> 4) + 1;
        for (int t = wv; t < nkt; t += 4) {
            const int k0 = t * 16;
            const unsigned short* bh = kih + ((size_t)(k0 + mrow)) * DI + kgrp * 8;
            const unsigned short* bl = kil + ((size_t)(k0 + mrow)) * DI + kgrp * 8;
            f32x4 acc = {0.f, 0.f, 0.f, 0.f};
#pragma unroll
            for (int dc = 0; dc < 4; dc++) {
                short8 Bh = *(const short8*)(bh + dc * 32);
                short8 Bl = *(const short8*)(bl + dc * 32);
                acc = __builtin_amdgcn_mfma_f32_16x16x32_bf16(Ah[dc], Bh, acc, 0, 0, 0);
                acc = __builtin_amdgcn_mfma_f32_16x16x32_bf16(Ah[dc], Bl, acc, 0, 0, 0);
            }
            float part = wreg[0] * fmaxf(acc[0], 0.f) + wreg[1] * fmaxf(acc[1], 0.f)
                       + wreg[2] * fmaxf(acc[2], 0.f) + wreg[3] * fmaxf(acc[3], 0.f);
            part += __shfl_xor(part, 16);
            part += __shfl_xor(part, 32);
            if (lane < 16) {
                int k = k0 + lane;
                if (k <= q) scores[k] = part;
            }
        }
        __syncthreads();
        topk_from_scores(scores, q + 1, K, q, topk_idx, topk_score, bins, sh_u, &cnt);
    }
}

// ---------------- Kernel A fallback: f32 VALU indexer + radix top-k ----------------
__global__ __launch_bounds__(256) void indexer_topk(
    const float* __restrict__ qi,
    const float* __restrict__ ki,
    const float* __restrict__ w,
    const int* __restrict__ topk_p, const int* __restrict__ endpos_p,
    int* __restrict__ topk_idx,
    float* __restrict__ topk_score)
{
    const int q   = blockIdx.x;
    const int tid = threadIdx.x;
    int K = min(topk_p[0], endpos_p[0]);
    K = min(K, KSEL);

    __shared__ float qis[HI * DI];
    __shared__ float wsh[HI];
    __shared__ float scores[S];
    __shared__ unsigned int bins[256];
    __shared__ unsigned int sh_u[3];
    __shared__ unsigned int cnt;

    for (int i = tid; i < HI * DI; i += 256) qis[i] = qi[(size_t)q * HI * DI + i];
    if (tid < HI) wsh[tid] = w[q * HI + tid];
    __syncthreads();

    const int ncand = q + 1;

    for (int kbase = 0; kbase < ncand; kbase += 1024) {
        const int k0 = kbase + tid * 4;
        if (k0 < ncand) {
            float acc[4][HI];
#pragma unroll
            for (int a = 0; a < 4; a++)
#pragma unroll
                for (int h = 0; h < HI; h++) acc[a][h] = 0.f;
            for (int d0 = 0; d0 < DI; d0 += 4) {
                float4 kv[4];
#pragma unroll
                for (int a = 0; a < 4; a++)
                    kv[a] = *(const float4*)&ki[(size_t)(k0 + a) * DI + d0];
#pragma unroll
                for (int h = 0; h < HI; h++) {
                    float4 qv = *(const float4*)&qis[h * DI + d0];
#pragma unroll
                    for (int a = 0; a < 4; a++) {
                        acc[a][h] += qv.x * kv[a].x + qv.y * kv[a].y +
                                     qv.z * kv[a].z + qv.w * kv[a].w;
                    }
                }
            }
#pragma unroll
            for (int a = 0; a < 4; a++) {
                int k = k0 + a;
                if (k < ncand) {
                    float s = 0.f;
#pragma unroll
                    for (int h = 0; h < HI; h++) s += wsh[h] * fmaxf(acc[a][h], 0.f);
                    scores[k] = s;
                }
            }
        }
    }
    __syncthreads();
    topk_from_scores(scores, ncand, K, q, topk_idx, topk_score, bins, sh_u, &cnt);
}

// ---------------- Kernel B v8: single fused gather loop (QK + exp + PV) ----------------
__global__ __launch_bounds__(256) void sparse_attn_v8(
    const float* __restrict__ Q,            // [HQ, S, D] f32
    const unsigned short* __restrict__ Kh,  // [HQ, S, D] f16
    const unsigned char* __restrict__ Vq,   // [HQ, S, D] fp8 e4m3
    const int* __restrict__ topk_idx,
    const int* __restrict__ topk_p, const int* __restrict__ endpos_p,
    float* __restrict__ out,                // [HQ, S, D] f32
    float* __restrict__ aacc_g)             // [S, KSEL]
{
    const int q   = blockIdx.x;
    const int h   = blockIdx.y;
    const int tid = threadIdx.x;
    int K = min(topk_p[0], endpos_p[0]);
    K = min(K, KSEL);
    const int n = min(q + 1, K);
    const float scale = 0.08838834764831845f;

    __shared__ int          offs[KSEL];      // K-row byte offsets (idx*256)
    __shared__ float        sc[KSEL];        // unnormalized p
    __shared__ unsigned int qh_u[64];        // Q row (pre-scaled) as 64 half2
    __shared__ float        opart[16][OPW];  // 8.4 KB (wave pre-reduced)
    __shared__ float        tmp[4];

    if (tid < 32) {
        float4 f = ((const float4*)&Q[((size_t)h * S + q) * D])[tid];
        qh_u[2 * tid]     = __builtin_bit_cast(unsigned int,
                              __floats2half2_rn(f.x * scale, f.y * scale));
        qh_u[2 * tid + 1] = __builtin_bit_cast(unsigned int,
                              __floats2half2_rn(f.z * scale, f.w * scale));
    }
    for (int j = tid; j < n; j += 256) offs[j] = topk_idx[q * KSEL + j] << 8;
    __syncthreads();

    const int l8 = tid & 7, grp8 = tid >> 3;   // 32 row-groups of 8 lanes
    unsigned int qa[4], qb[4];
#pragma unroll
    for (int c = 0; c < 4; c++) {
        qa[c] = qh_u[l8 * 4 + c];
        qb[c] = qh_u[32 + l8 * 4 + c];
    }
    const char* kbase = (const char*)Kh + (size_t)h * S * 256;
    const char* vbase = (const char*)Vq + (size_t)h * S * 128;

    // ---- fused loop: score -> p -> PV accumulate ----
    float lsum = 0.f;
    f32x2 o2[8];
#pragma unroll
    for (int i = 0; i < 8; i++) o2[i] = (f32x2){0.f, 0.f};
    for (int j = grp8; j < n; j += 32) {
        const int off = offs[j];
        const char* rb = kbase + off;
        uint4 ra   = *(const uint4*)(rb + l8 * 16);
        uint4 rb2  = *(const uint4*)(rb + 128 + l8 * 16);
        uint4 vraw = *(const uint4*)(vbase + (off >> 1) + l8 * 16);
        float acc0 = fdot2u(ra.x, qa[0], 0.f);
        float acc1 = fdot2u(rb2.x, qb[0], 0.f);
        acc0 = fdot2u(ra.y, qa[1], acc0);
        acc1 = fdot2u(rb2.y, qb[1], acc1);
        acc0 = fdot2u(ra.z, qa[2], acc0);
        acc1 = fdot2u(rb2.z, qb[2], acc1);
        acc0 = fdot2u(ra.w, qa[3], acc0);
        acc1 = fdot2u(rb2.w, qb[3], acc1);
        float acc = acc0 + acc1;
        acc += __shfl_xor(acc, 1);
        acc += __shfl_xor(acc, 2);
        acc += __shfl_xor(acc, 4);
        const float p = __expf(acc);         // all 8 lanes (trans pipe)
        if (l8 == 0) sc[j] = p;
        lsum += p;                           // 8x-counted, rescaled below
        const f32x2 p2 = {p, p};
        o2[0] += p2 * __builtin_amdgcn_cvt_pk_f32_fp8((int)vraw.x, false);
        o2[1] += p2 * __builtin_amdgcn_cvt_pk_f32_fp8((int)vraw.x, true);
        o2[2] += p2 * __builtin_amdgcn_cvt_pk_f32_fp8((int)vraw.y, false);
        o2[3] += p2 * __builtin_amdgcn_cvt_pk_f32_fp8((int)vraw.y, true);
        o2[4] += p2 * __builtin_amdgcn_cvt_pk_f32_fp8((int)vraw.z, false);
        o2[5] += p2 * __builtin_amdgcn_cvt_pk_f32_fp8((int)vraw.z, true);
        o2[6] += p2 * __builtin_amdgcn_cvt_pk_f32_fp8((int)vraw.w, false);
        o2[7] += p2 * __builtin_amdgcn_cvt_pk_f32_fp8((int)vraw.w, true);
    }
    lsum = blockReduceSum(lsum, tmp) * 0.125f;   // undo 8x (exact)
    const float inv = 1.f / lsum;

    // ---- aacc (head-summed normalized attn) ----
    for (int j = tid; j < n; j += 256)
        atomicAdd(&aacc_g[(size_t)q * KSEL + j], sc[j] * inv);

    // ---- PV epilogue: wave pre-reduce + LDS cross-wave reduce ----
#pragma unroll
    for (int i = 0; i < 8; i++) o2[i] += f2shfl_xor(o2[i], 32);
    const int lane = tid & 63, wvi = tid >> 6;
    if (lane < 32) {
        const int row = wvi * 4 + (lane >> 3);
        float* dst = &opart[row][(lane & 7) * 16];
#pragma unroll
        for (int i = 0; i < 8; i += 2) {
            float4 s;
            s.x = o2[i].x;     s.y = o2[i].y;
            s.z = o2[i + 1].x; s.w = o2[i + 1].y;
            *(float4*)&dst[i * 2] = s;
        }
    }
    __syncthreads();
    if (tid < D) {
        float s = 0.f;
#pragma unroll
        for (int p16 = 0; p16 < 16; ++p16) s += opart[p16][tid];
        out[((size_t)h * S + q) * D + tid] = s * inv;
    }
}

// ---------------- Kernel B (f32 fallback, ws too small) ----------------
__global__ __launch_bounds__(256) void sparse_attn2(
    const float* __restrict__ Q,
    const float* __restrict__ Km,
    const float* __restrict__ V,
    const int* __restrict__ topk_idx,
    const int* __restrict__ topk_p, const int* __restrict__ endpos_p,
    float* __restrict__ out,
    float* __restrict__ aacc_g)
{
    const int q   = blockIdx.x;
    const int h   = blockIdx.y;
    const int tid = threadIdx.x;
    int K = min(topk_p[0], endpos_p[0]);
    K = min(K, KSEL);
    const int n = min(q + 1, K);
    const float scale = 0.08838834764831845f;

    __shared__ float qvec[D];
    __shared__ int   idxs[KSEL];
    __shared__ float sc[KSEL];
    __shared__ float opart[8][D];
    __shared__ float tmp[4];

    if (tid < 32)
        *(float4*)&qvec[tid * 4] = *(const float4*)&Q[((size_t)h * S + q) * D + tid * 4];
    for (int j = tid; j < n; j += 256) idxs[j] = topk_idx[q * KSEL + j];
    __syncthreads();

    const int l16 = tid & 15, grp = tid >> 4;
    const float4 q1 = *(const float4*)&qvec[l16 * 4];
    const float4 q2 = *(const float4*)&qvec[64 + l16 * 4];
    float lmax = -INFINITY;
    for (int j = grp; j < n; j += 16) {
        const float* kr = &Km[((size_t)h * S + idxs[j]) * D];
        float4 k1 = *(const float4*)&kr[l16 * 4];
        float4 k2 = *(const float4*)&kr[64 + l16 * 4];
        float acc = q1.x * k1.x + q1.y * k1.y + q1.z * k1.z + q1.w * k1.w
                  + q2.x * k2.x + q2.y * k2.y + q2.z * k2.z + q2.w * k2.w;
        acc += __shfl_xor(acc, 1);
        acc += __shfl_xor(acc, 2);
        acc += __shfl_xor(acc, 4);
        acc += __shfl_xor(acc, 8);
        float s = acc * scale;
        if (l16 == 0) sc[j] = s;
        lmax = fmaxf(lmax, s);
    }
    const float m = blockReduceMax(lmax, tmp);

    float lsum = 0.f;
    for (int j = tid; j < n; j += 256) {
        float p = expf(sc[j] - m);
        sc[j] = p;
        lsum += p;
    }
    lsum = blockReduceSum(lsum, tmp);
    const float inv = 1.f / lsum;
    for (int j = tid; j < n; j += 256) {
        float p = sc[j] * inv;
        sc[j] = p;
        atomicAdd(&aacc_g[(size_t)q * KSEL + j], p);
    }
    __syncthreads();

    const int jg = tid >> 5, lD = (tid & 31) * 4;
    float4 o4 = make_float4(0.f, 0.f, 0.f, 0.f);
    for (int j = jg; j < n; j += 8) {
        const float p = sc[j];
        float4 vv = *(const float4*)&V[((size_t)h * S + idxs[j]) * D + lD];
        o4.x += p * vv.x; o4.y += p * vv.y; o4.z += p * vv.z; o4.w += p * vv.w;
    }
    *(float4*)&opart[jg][lD] = o4;
    __syncthreads();
    if (tid < D) {
        float o = 0.f;
#pragma unroll
        for (int p8 = 0; p8 < 8; ++p8) o += opart[p8][tid];
        out[((size_t)h * S + q) * D + tid] = o;
    }
}

// ---------------- Kernel B2: per-row KL loss ----------------
__global__ __launch_bounds__(256) void row_loss(
    const float* __restrict__ aacc_g,
    const float* __restrict__ topk_score,
    const int* __restrict__ topk_p, const int* __restrict__ endpos_p,
    float* __restrict__ rowloss)
{
    const int q   = blockIdx.x;
    const int tid = threadIdx.x;
    int K = min(topk_p[0], endpos_p[0]);
    K = min(K, KSEL);
    const int n = min(q + 1, K);

    __shared__ float sc[KSEL];
    __shared__ float aacc[KSEL];
    __shared__ float tmp[4];

    for (int j = tid; j < n; j += 256) aacc[j] = aacc_g[(size_t)q * KSEL + j];

    float tmaxl = -INFINITY;
    for (int j = tid; j < n; j += 256) {
        float t = topk_score[q * KSEL + j];
        sc[j] = t;
        tmaxl = fmaxf(tmaxl, t);
    }
    const float tm = blockReduceMax(tmaxl, tmp);
    float tsum = 0.f;
    for (int j = tid; j < n; j += 256) {
        float e = __expf(sc[j] - tm);
        sc[j] = e;
        tsum += e;
    }
    tsum = blockReduceSum(tsum, tmp);
    const float tinv = 1.f / tsum;

    float sa = 0.f;
    for (int j = tid; j < n; j += 256) sa += fabsf(aacc[j]);
    sa = blockReduceSum(sa, tmp);
    const float denom = fmaxf(sa, 1e-12f);

    float kl = 0.f;
    for (int j = tid; j < n; j += 256) {
        float tgt = aacc[j] / denom + 1e-8f;
        float pd  = sc[j] * tinv + 1e-8f;
        kl += tgt * (__logf(tgt) - __logf(pd));
    }
    kl = blockReduceSum(kl, tmp);
    if (tid == 0) rowloss[q] = kl;
}

// ---------------- Kernel C: loss = mean over rows ----------------
__global__ __launch_bounds__(256) void reduce_loss(const float* __restrict__ rowloss,
                                                   float* __restrict__ out) {
    __shared__ float tmp[4];
    float v = 0.f;
    for (int i = threadIdx.x; i < S; i += 256) v += rowloss[i];
    v = blockReduceSum(v, tmp);
    if (threadIdx.x == 0) out[0] = v / (float)S;
}

extern "C" void kernel_launch(void* const* d_in, const int* in_sizes, int n_in,
                              void* d_out, int out_size, void* d_ws, size_t ws_size,
                              hipStream_t stream) {
    const float* q   = (const float*)d_in[0];
    const float* k   = (const float*)d_in[1];
    const float* v   = (const float*)d_in[2];
    const float* qi  = (const float*)d_in[3];
    const float* ki  = (const float*)d_in[4];
    const float* w   = (const float*)d_in[5];
    const int* topk  = (const int*)d_in[6];
    const int* endp  = (const int*)d_in[7];
    float* out = (float*)d_out;

    char* ws = (char*)d_ws;
    const size_t MB = 1ull << 20;
    int*   topk_idx   = (int*)ws;                             // 4 MB
    float* topk_score = (float*)(ws + 4 * MB);                // 4 MB
    float* aacc_g     = (float*)(ws + 8 * MB);                // 4 MB
    float* rowloss    = (float*)(ws + 12 * MB);               // 64 KB
    char*  pbuf       = ws + 12 * MB + 65536;
    unsigned short* Kh  = (unsigned short*)pbuf;                    // 8 MB f16
    unsigned char*  Vq  = (unsigned char*)(pbuf + 8 * MB);          // 4 MB fp8
    unsigned short* qih = (unsigned short*)(pbuf + 12 * MB);        // 8 MB
    unsigned short* qil = (unsigned short*)(pbuf + 20 * MB);        // 8 MB
    unsigned short* kih = (unsigned short*)(pbuf + 28 * MB);        // 512 KB
    unsigned short* kil = (unsigned short*)(pbuf + 28 * MB + 512 * 1024); // 512 KB
    const size_t need_attn = 12 * MB + 65536 + 12 * MB;
    const size_t need_idx  = 12 * MB + 65536 + 29 * MB;

    if (ws_size >= need_idx && ws_size >= need_attn) {
        // fused fast path: one prep kernel (splits + converts + aacc zero)
        hipLaunchKernelGGL(prep_all, dim3(2048), dim3(256), 0, stream,
                           k, v, Kh, (unsigned int*)Vq,
                           qi, qih, qil, ki, kih, kil, aacc_g,
                           HQ * S * D / 4, S * HI * DI / 4, S * DI / 4,
                           S * KSEL / 4);
        hipLaunchKernelGGL(indexer_mfma, dim3(S / 2), dim3(256), 0, stream,
                           qih, qil, kih, kil, w, topk, endp, topk_idx, topk_score);
        hipLaunchKernelGGL(sparse_attn_v8, dim3(S, HQ), dim3(256), 0, stream,
                           q, Kh, Vq, topk_idx, topk, endp, out + 1, aacc_g);
    } else {
        hipLaunchKernelGGL(indexer_topk, dim3(S), dim3(256), 0, stream,
                           qi, ki, w, topk, endp, topk_idx, topk_score);
        hipMemsetAsync(aacc_g, 0, (size_t)S * KSEL * sizeof(float), stream);
        hipLaunchKernelGGL(sparse_attn2, dim3(S, HQ), dim3(256), 0, stream,
                           q, k, v, topk_idx, topk, endp, out + 1, aacc_g);
    }

    hipLaunchKernelGGL(row_loss, dim3(S), dim3(256), 0, stream,
                       aacc_g, topk_score, topk, endp, rowloss);
    hipLaunchKernelGGL(reduce_loss, dim3(1), dim3(256), 0, stream,
                       rowloss, out);
}

// Round 23
// 373.892 us; speedup vs baseline: 1.0277x; 1.0277x over previous
//
#include <hip/hip_runtime.h>
#include <hip/hip_bf16.h>
#include <hip/hip_fp16.h>
#include <math.h>

#define S    2048
#define HQ   16
#define D    128
#define HI   16
#define DI   128
#define KSEL 512
#define OPW  132   // opart row stride (floats)

typedef __attribute__((ext_vector_type(8))) short short8;
typedef __attribute__((ext_vector_type(4))) float f32x4;
typedef __attribute__((ext_vector_type(2))) float f32x2;
typedef __attribute__((ext_vector_type(2))) _Float16 h2v;

// ---------------- reductions (wave = 64) ----------------
__device__ __forceinline__ float waveReduceSum(float v) {
#pragma unroll
    for (int o = 32; o > 0; o >>= 1) v += __shfl_down(v, o);
    return v;
}
__device__ __forceinline__ float waveReduceMax(float v) {
#pragma unroll
    for (int o = 32; o > 0; o >>= 1) v = fmaxf(v, __shfl_down(v, o));
    return v;
}
__device__ __forceinline__ float blockReduceSum(float v, float* tmp) {
    int wid = threadIdx.x >> 6, lane = threadIdx.x & 63;
    v = waveReduceSum(v);
    __syncthreads();
    if (lane == 0) tmp[wid] = v;
    __syncthreads();
    return tmp[0] + tmp[1] + tmp[2] + tmp[3];
}
__device__ __forceinline__ float blockReduceMax(float v, float* tmp) {
    int wid = threadIdx.x >> 6, lane = threadIdx.x & 63;
    v = waveReduceMax(v);
    __syncthreads();
    if (lane == 0) tmp[wid] = v;
    __syncthreads();
    return fmaxf(fmaxf(tmp[0], tmp[1]), fmaxf(tmp[2], tmp[3]));
}

__device__ __forceinline__ unsigned short f2bf(float f) {  // RNE
    unsigned int u = __float_as_uint(f);
    return (unsigned short)((u + 0x7FFFu + ((u >> 16) & 1u)) >> 16);
}
__device__ __forceinline__ float bf2f(unsigned short h) {
    return __uint_as_float(((unsigned int)h) << 16);
}
__device__ __forceinline__ float fdot2u(unsigned int a, unsigned int b, float c) {
    return __builtin_amdgcn_fdot2(__builtin_bit_cast(h2v, a),
                                  __builtin_bit_cast(h2v, b), c, false);
}
__device__ __forceinline__ f32x2 f2shfl_xor(f32x2 v, int m) {
    f32x2 r;
    r.x = __shfl_xor(v.x, m);
    r.y = __shfl_xor(v.y, m);
    return r;
}
__device__ __forceinline__ void split4(const float* in, unsigned short* hi,
                                       unsigned short* lo, int i) {
    float4 x = ((const float4*)in)[i];
    ushort4 h4, l4;
    h4.x = f2bf(x.x); l4.x = f2bf(x.x - bf2f(h4.x));
    h4.y = f2bf(x.y); l4.y = f2bf(x.y - bf2f(h4.y));
    h4.z = f2bf(x.z); l4.z = f2bf(x.z - bf2f(h4.z));
    h4.w = f2bf(x.w); l4.w = f2bf(x.w - bf2f(h4.w));
    ((ushort4*)hi)[i] = h4;
    ((ushort4*)lo)[i] = l4;
}

// ---------------- fused prep: K->f16, V->fp8, qi/ki bf16-split, zero aacc ----------------
__global__ __launch_bounds__(256) void prep_all(
    const float* __restrict__ kin, const float* __restrict__ vin,
    unsigned short* __restrict__ Kh, unsigned int* __restrict__ Vq,
    const float* __restrict__ qi, unsigned short* __restrict__ qih,
    unsigned short* __restrict__ qil,
    const float* __restrict__ ki, unsigned short* __restrict__ kih,
    unsigned short* __restrict__ kil,
    float* __restrict__ aacc_g,
    int n4kv, int n4q, int n4k, int n4acc) {
    const int stride = gridDim.x * 256;
    const int t0 = blockIdx.x * 256 + threadIdx.x;
    for (int i = t0; i < n4kv; i += stride) {
        float4 x = ((const float4*)kin)[i];
        uint2 r;
        r.x = __builtin_bit_cast(unsigned int, __floats2half2_rn(x.x, x.y));
        r.y = __builtin_bit_cast(unsigned int, __floats2half2_rn(x.z, x.w));
        ((uint2*)Kh)[i] = r;
        float4 y = ((const float4*)vin)[i];
        int u = 0;
        u = __builtin_amdgcn_cvt_pk_fp8_f32(y.x, y.y, u, false);
        u = __builtin_amdgcn_cvt_pk_fp8_f32(y.z, y.w, u, true);
        Vq[i] = (unsigned int)u;
    }
    for (int i = t0; i < n4q; i += stride) split4(qi, qih, qil, i);
    for (int i = t0; i < n4k; i += stride) split4(ki, kih, kil, i);
    float4 z = make_float4(0.f, 0.f, 0.f, 0.f);
    for (int i = t0; i < n4acc; i += stride) ((float4*)aacc_g)[i] = z;
}

// ---------------- shared device radix top-k (scores in LDS, >= 0) ----------------
__device__ void topk_from_scores(const float* scores, int ncand, int K, int q,
                                 int* __restrict__ topk_idx, float* __restrict__ topk_score,
                                 unsigned int* bins, unsigned int* sh_u, unsigned int* cnt_p) {
    const int tid = threadIdx.x;
    if (ncand <= K) {
        for (int j = tid; j < KSEL; j += 256) {
            if (j < ncand) {
                topk_idx[q * KSEL + j]   = j;
                topk_score[q * KSEL + j] = scores[j];
            } else {
                topk_idx[q * KSEL + j]   = -1;
                topk_score[q * KSEL + j] = -INFINITY;
            }
        }
        __syncthreads();
        return;
    }

    unsigned int prefix = 0;
    int need = K;
    for (int pass = 0; pass < 4; ++pass) {
        const int shift = 24 - pass * 8;
        for (int b = tid; b < 256; b += 256) bins[b] = 0;
        __syncthreads();
        const unsigned int himask = (pass == 0) ? 0u : (0xFFFFFFFFu << (shift + 8));
        for (int k = tid; k < ncand; k += 256) {
            unsigned int u = __float_as_uint(scores[k]);
            if ((u & himask) == prefix) atomicAdd(&bins[(u >> shift) & 0xFF], 1u);
        }
        __syncthreads();
        if (tid < 64) {
            const int l = tid;
            unsigned int b0 = bins[4 * l], b1 = bins[4 * l + 1],
                         b2 = bins[4 * l + 2], b3 = bins[4 * l + 3];
            unsigned int s3 = b3, s2 = b2 + s3, s1 = b1 + s2, s0 = b0 + s1;
            unsigned int acc = s0;
#pragma unroll
            for (int off = 1; off < 64; off <<= 1) {
                unsigned int t = __shfl_down(acc, off);
                if (l + off < 64) acc += t;
            }
            const unsigned int above = acc - s0;
            const unsigned int S0 = s0 + above, S1 = s1 + above,
                               S2 = s2 + above, S3 = s3 + above;
            const unsigned int nd = (unsigned int)need;
            if (4 * l + 0 >= 1 && S0 >= nd && S1 < nd) {
                sh_u[0] = prefix | ((unsigned int)(4 * l + 0) << shift);
                sh_u[1] = nd - S1;
            }
            if (S1 >= nd && S2 < nd) {
                sh_u[0] = prefix | ((unsigned int)(4 * l + 1) << shift);
                sh_u[1] = nd - S2;
            }
            if (S2 >= nd && S3 < nd) {
                sh_u[0] = prefix | ((unsigned int)(4 * l + 2) << shift);
                sh_u[1] = nd - S3;
            }
            if (S3 >= nd && above < nd) {
                sh_u[0] = prefix | ((unsigned int)(4 * l + 3) << shift);
                sh_u[1] = nd - above;
            }
            if (l == 0 && S1 < nd) {
                sh_u[0] = prefix;
                sh_u[1] = nd - S1;
            }
        }
        __syncthreads();
        prefix = sh_u[0];
        need   = (int)sh_u[1];
        __syncthreads();
    }
    const unsigned int ueqT = prefix;
    const int count_eq = (int)bins[ueqT & 0xFF];
    __syncthreads();
    if (tid == 0) *cnt_p = 0;
    __syncthreads();

    for (int k = tid; k < ncand; k += 256) {
        unsigned int u = __float_as_uint(scores[k]);
        if (u > ueqT) {
            unsigned int slot = atomicAdd(cnt_p, 1u);
            topk_idx[q * KSEL + slot]   = k;
            topk_score[q * KSEL + slot] = scores[k];
        }
    }
    __syncthreads();
    if (count_eq == need) {
        for (int k = tid; k < ncand; k += 256) {
            if (__float_as_uint(scores[k]) == ueqT) {
                unsigned int slot = atomicAdd(cnt_p, 1u);
                topk_idx[q * KSEL + slot]   = k;
                topk_score[q * KSEL + slot] = __uint_as_float(ueqT);
            }
        }
    } else if (tid == 0) {
        int emitted = 0;
        for (int k = 0; k < ncand && emitted < need; ++k) {
            if (__float_as_uint(scores[k]) == ueqT) {
                unsigned int slot = atomicAdd(cnt_p, 1u);
                topk_idx[q * KSEL + slot]   = k;
                topk_score[q * KSEL + slot] = __uint_as_float(ueqT);
                emitted++;
            }
        }
    }
    __syncthreads();
}

// ---------------- Kernel A (MFMA): indexer via 3-term split-bf16 MFMA + radix topk ----------------
// 3-term split: AhBh + AhBl + AlBh (verified config; 2-term raised absmax to 0.21)
__global__ __launch_bounds__(256) void indexer_mfma(
    const unsigned short* __restrict__ qih, const unsigned short* __restrict__ qil,
    const unsigned short* __restrict__ kih, const unsigned short* __restrict__ kil,
    const float* __restrict__ w,
    const int* __restrict__ topk_p, const int* __restrict__ endpos_p,
    int* __restrict__ topk_idx, float* __restrict__ topk_score)
{
    const int tid  = threadIdx.x;
    const int wv   = tid >> 6;
    const int lane = tid & 63;
    int K = min(topk_p[0], endpos_p[0]);
    K = min(K, KSEL);

    __shared__ float scores[S];
    __shared__ float w_sh[HI];
    __shared__ unsigned int bins[256];
    __shared__ unsigned int sh_u[3];
    __shared__ unsigned int cnt;

    const int mrow = lane & 15;
    const int kgrp = lane >> 4;

    const int b = blockIdx.x;
    for (int qq = 0; qq < 2; ++qq) {
        const int q = qq ? (S - 1 - b) : b;
        if (tid < HI) w_sh[tid] = w[q * HI + tid];
        __syncthreads();

        short8 Ah[4], Al[4];
        {
            const unsigned short* bh = qih + ((size_t)q * HI + mrow) * DI + kgrp * 8;
            const unsigned short* bl = qil + ((size_t)q * HI + mrow) * DI + kgrp * 8;
#pragma unroll
            for (int dc = 0; dc < 4; dc++) {
                Ah[dc] = *(const short8*)(bh + dc * 32);
                Al[dc] = *(const short8*)(bl + dc * 32);
            }
        }
        float wreg[4];
#pragma unroll
        for (int e = 0; e < 4; e++) wreg[e] = w_sh[4 * kgrp + e];

        const int nkt = (q >> 4) + 1;
        for (int t = wv; t < nkt; t += 4) {
            const int k0 = t * 16;
            const unsigned short* bh = kih + ((size_t)(k0 + mrow)) * DI + kgrp * 8;
            const unsigned short* bl = kil + ((size_t)(k0 + mrow)) * DI + kgrp * 8;
            f32x4 acc = {0.f, 0.f, 0.f, 0.f};
#pragma unroll
            for (int dc = 0; dc < 4; dc++) {
                short8 Bh = *(const short8*)(bh + dc * 32);
                short8 Bl = *(const short8*)(bl + dc * 32);
                acc = __builtin_amdgcn_mfma_f32_16x16x32_bf16(Ah[dc], Bh, acc, 0, 0, 0);
                acc = __builtin_amdgcn_mfma_f32_16x16x32_bf16(Ah[dc], Bl, acc, 0, 0, 0);
                acc = __builtin_amdgcn_mfma_f32_16x16x32_bf16(Al[dc], Bh, acc, 0, 0, 0);
            }
            float part = wreg[0] * fmaxf(acc[0], 0.f) + wreg[1] * fmaxf(acc[1], 0.f)
                       + wreg[2] * fmaxf(acc[2], 0.f) + wreg[3] * fmaxf(acc[3], 0.f);
            part += __shfl_xor(part, 16);
            part += __shfl_xor(part, 32);
            if (lane < 16) {
                int k = k0 + lane;
                if (k <= q) scores[k] = part;
            }
        }
        __syncthreads();
        topk_from_scores(scores, q + 1, K, q, topk_idx, topk_score, bins, sh_u, &cnt);
    }
}

// ---------------- Kernel A fallback: f32 VALU indexer + radix top-k ----------------
__global__ __launch_bounds__(256) void indexer_topk(
    const float* __restrict__ qi,
    const float* __restrict__ ki,
    const float* __restrict__ w,
    const int* __restrict__ topk_p, const int* __restrict__ endpos_p,
    int* __restrict__ topk_idx,
    float* __restrict__ topk_score)
{
    const int q   = blockIdx.x;
    const int tid = threadIdx.x;
    int K = min(topk_p[0], endpos_p[0]);
    K = min(K, KSEL);

    __shared__ float qis[HI * DI];
    __shared__ float wsh[HI];
    __shared__ float scores[S];
    __shared__ unsigned int bins[256];
    __shared__ unsigned int sh_u[3];
    __shared__ unsigned int cnt;

    for (int i = tid; i < HI * DI; i += 256) qis[i] = qi[(size_t)q * HI * DI + i];
    if (tid < HI) wsh[tid] = w[q * HI + tid];
    __syncthreads();

    const int ncand = q + 1;

    for (int kbase = 0; kbase < ncand; kbase += 1024) {
        const int k0 = kbase + tid * 4;
        if (k0 < ncand) {
            float acc[4][HI];
#pragma unroll
            for (int a = 0; a < 4; a++)
#pragma unroll
                for (int h = 0; h < HI; h++) acc[a][h] = 0.f;
            for (int d0 = 0; d0 < DI; d0 += 4) {
                float4 kv[4];
#pragma unroll
                for (int a = 0; a < 4; a++)
                    kv[a] = *(const float4*)&ki[(size_t)(k0 + a) * DI + d0];
#pragma unroll
                for (int h = 0; h < HI; h++) {
                    float4 qv = *(const float4*)&qis[h * DI + d0];
#pragma unroll
                    for (int a = 0; a < 4; a++) {
                        acc[a][h] += qv.x * kv[a].x + qv.y * kv[a].y +
                                     qv.z * kv[a].z + qv.w * kv[a].w;
                    }
                }
            }
#pragma unroll
            for (int a = 0; a < 4; a++) {
                int k = k0 + a;
                if (k < ncand) {
                    float s = 0.f;
#pragma unroll
                    for (int h = 0; h < HI; h++) s += wsh[h] * fmaxf(acc[a][h], 0.f);
                    scores[k] = s;
                }
            }
        }
    }
    __syncthreads();
    topk_from_scores(scores, ncand, K, q, topk_idx, topk_score, bins, sh_u, &cnt);
}

// ---------------- Kernel B v8: single fused gather loop (QK + exp + PV) ----------------
__global__ __launch_bounds__(256) void sparse_attn_v8(
    const float* __restrict__ Q,            // [HQ, S, D] f32
    const unsigned short* __restrict__ Kh,  // [HQ, S, D] f16
    const unsigned char* __restrict__ Vq,   // [HQ, S, D] fp8 e4m3
    const int* __restrict__ topk_idx,
    const int* __restrict__ topk_p, const int* __restrict__ endpos_p,
    float* __restrict__ out,                // [HQ, S, D] f32
    float* __restrict__ aacc_g)             // [S, KSEL]
{
    const int q   = blockIdx.x;
    const int h   = blockIdx.y;
    const int tid = threadIdx.x;
    int K = min(topk_p[0], endpos_p[0]);
    K = min(K, KSEL);
    const int n = min(q + 1, K);
    const float scale = 0.08838834764831845f;

    __shared__ int          offs[KSEL];      // K-row byte offsets (idx*256)
    __shared__ float        sc[KSEL];        // unnormalized p
    __shared__ unsigned int qh_u[64];        // Q row (pre-scaled) as 64 half2
    __shared__ float        opart[16][OPW];  // 8.4 KB (wave pre-reduced)
    __shared__ float        tmp[4];

    if (tid < 32) {
        float4 f = ((const float4*)&Q[((size_t)h * S + q) * D])[tid];
        qh_u[2 * tid]     = __builtin_bit_cast(unsigned int,
                              __floats2half2_rn(f.x * scale, f.y * scale));
        qh_u[2 * tid + 1] = __builtin_bit_cast(unsigned int,
                              __floats2half2_rn(f.z * scale, f.w * scale));
    }
    for (int j = tid; j < n; j += 256) offs[j] = topk_idx[q * KSEL + j] << 8;
    __syncthreads();

    const int l8 = tid & 7, grp8 = tid >> 3;   // 32 row-groups of 8 lanes
    unsigned int qa[4], qb[4];
#pragma unroll
    for (int c = 0; c < 4; c++) {
        qa[c] = qh_u[l8 * 4 + c];
        qb[c] = qh_u[32 + l8 * 4 + c];
    }
    const char* kbase = (const char*)Kh + (size_t)h * S * 256;
    const char* vbase = (const char*)Vq + (size_t)h * S * 128;

    // ---- fused loop: score -> p -> PV accumulate ----
    float lsum = 0.f;
    f32x2 o2[8];
#pragma unroll
    for (int i = 0; i < 8; i++) o2[i] = (f32x2){0.f, 0.f};
    for (int j = grp8; j < n; j += 32) {
        const int off = offs[j];
        const char* rb = kbase + off;
        uint4 ra   = *(const uint4*)(rb + l8 * 16);
        uint4 rb2  = *(const uint4*)(rb + 128 + l8 * 16);
        uint4 vraw = *(const uint4*)(vbase + (off >> 1) + l8 * 16);
        float acc0 = fdot2u(ra.x, qa[0], 0.f);
        float acc1 = fdot2u(rb2.x, qb[0], 0.f);
        acc0 = fdot2u(ra.y, qa[1], acc0);
        acc1 = fdot2u(rb2.y, qb[1], acc1);
        acc0 = fdot2u(ra.z, qa[2], acc0);
        acc1 = fdot2u(rb2.z, qb[2], acc1);
        acc0 = fdot2u(ra.w, qa[3], acc0);
        acc1 = fdot2u(rb2.w, qb[3], acc1);
        float acc = acc0 + acc1;
        acc += __shfl_xor(acc, 1);
        acc += __shfl_xor(acc, 2);
        acc += __shfl_xor(acc, 4);
        const float p = __expf(acc);         // all 8 lanes (trans pipe)
        if (l8 == 0) sc[j] = p;
        lsum += p;                           // 8x-counted, rescaled below
        const f32x2 p2 = {p, p};
        o2[0] += p2 * __builtin_amdgcn_cvt_pk_f32_fp8((int)vraw.x, false);
        o2[1] += p2 * __builtin_amdgcn_cvt_pk_f32_fp8((int)vraw.x, true);
        o2[2] += p2 * __builtin_amdgcn_cvt_pk_f32_fp8((int)vraw.y, false);
        o2[3] += p2 * __builtin_amdgcn_cvt_pk_f32_fp8((int)vraw.y, true);
        o2[4] += p2 * __builtin_amdgcn_cvt_pk_f32_fp8((int)vraw.z, false);
        o2[5] += p2 * __builtin_amdgcn_cvt_pk_f32_fp8((int)vraw.z, true);
        o2[6] += p2 * __builtin_amdgcn_cvt_pk_f32_fp8((int)vraw.w, false);
        o2[7] += p2 * __builtin_amdgcn_cvt_pk_f32_fp8((int)vraw.w, true);
    }
    lsum = blockReduceSum(lsum, tmp) * 0.125f;   // undo 8x (exact)
    const float inv = 1.f / lsum;

    // ---- aacc (head-summed normalized attn) ----
    for (int j = tid; j < n; j += 256)
        atomicAdd(&aacc_g[(size_t)q * KSEL + j], sc[j] * inv);

    // ---- PV epilogue: wave pre-reduce + LDS cross-wave reduce ----
#pragma unroll
    for (int i = 0; i < 8; i++) o2[i] += f2shfl_xor(o2[i], 32);
    const int lane = tid & 63, wvi = tid >> 6;
    if (lane < 32) {
        const int row = wvi * 4 + (lane >> 3);
        float* dst = &opart[row][(lane & 7) * 16];
#pragma unroll
        for (int i = 0; i < 8; i += 2) {
            float4 s;
            s.x = o2[i].x;     s.y = o2[i].y;
            s.z = o2[i + 1].x; s.w = o2[i + 1].y;
            *(float4*)&dst[i * 2] = s;
        }
    }
    __syncthreads();
    if (tid < D) {
        float s = 0.f;
#pragma unroll
        for (int p16 = 0; p16 < 16; ++p16) s += opart[p16][tid];
        out[((size_t)h * S + q) * D + tid] = s * inv;
    }
}

// ---------------- Kernel B (f32 fallback, ws too small) ----------------
__global__ __launch_bounds__(256) void sparse_attn2(
    const float* __restrict__ Q,
    const float* __restrict__ Km,
    const float* __restrict__ V,
    const int* __restrict__ topk_idx,
    const int* __restrict__ topk_p, const int* __restrict__ endpos_p,
    float* __restrict__ out,
    float* __restrict__ aacc_g)
{
    const int q   = blockIdx.x;
    const int h   = blockIdx.y;
    const int tid = threadIdx.x;
    int K = min(topk_p[0], endpos_p[0]);
    K = min(K, KSEL);
    const int n = min(q + 1, K);
    const float scale = 0.08838834764831845f;

    __shared__ float qvec[D];
    __shared__ int   idxs[KSEL];
    __shared__ float sc[KSEL];
    __shared__ float opart[8][D];
    __shared__ float tmp[4];

    if (tid < 32)
        *(float4*)&qvec[tid * 4] = *(const float4*)&Q[((size_t)h * S + q) * D + tid * 4];
    for (int j = tid; j < n; j += 256) idxs[j] = topk_idx[q * KSEL + j];
    __syncthreads();

    const int l16 = tid & 15, grp = tid >> 4;
    const float4 q1 = *(const float4*)&qvec[l16 * 4];
    const float4 q2 = *(const float4*)&qvec[64 + l16 * 4];
    float lmax = -INFINITY;
    for (int j = grp; j < n; j += 16) {
        const float* kr = &Km[((size_t)h * S + idxs[j]) * D];
        float4 k1 = *(const float4*)&kr[l16 * 4];
        float4 k2 = *(const float4*)&kr[64 + l16 * 4];
        float acc = q1.x * k1.x + q1.y * k1.y + q1.z * k1.z + q1.w * k1.w
                  + q2.x * k2.x + q2.y * k2.y + q2.z * k2.z + q2.w * k2.w;
        acc += __shfl_xor(acc, 1);
        acc += __shfl_xor(acc, 2);
        acc += __shfl_xor(acc, 4);
        acc += __shfl_xor(acc, 8);
        float s = acc * scale;
        if (l16 == 0) sc[j] = s;
        lmax = fmaxf(lmax, s);
    }
    const float m = blockReduceMax(lmax, tmp);

    float lsum = 0.f;
    for (int j = tid; j < n; j += 256) {
        float p = expf(sc[j] - m);
        sc[j] = p;
        lsum += p;
    }
    lsum = blockReduceSum(lsum, tmp);
    const float inv = 1.f / lsum;
    for (int j = tid; j < n; j += 256) {
        float p = sc[j] * inv;
        sc[j] = p;
        atomicAdd(&aacc_g[(size_t)q * KSEL + j], p);
    }
    __syncthreads();

    const int jg = tid >> 5, lD = (tid & 31) * 4;
    float4 o4 = make_float4(0.f, 0.f, 0.f, 0.f);
    for (int j = jg; j < n; j += 8) {
        const float p = sc[j];
        float4 vv = *(const float4*)&V[((size_t)h * S + idxs[j]) * D + lD];
        o4.x += p * vv.x; o4.y += p * vv.y; o4.z += p * vv.z; o4.w += p * vv.w;
    }
    *(float4*)&opart[jg][lD] = o4;
    __syncthreads();
    if (tid < D) {
        float o = 0.f;
#pragma unroll
        for (int p8 = 0; p8 < 8; ++p8) o += opart[p8][tid];
        out[((size_t)h * S + q) * D + tid] = o;
    }
}

// ---------------- Kernel B2: per-row KL loss ----------------
__global__ __launch_bounds__(256) void row_loss(
    const float* __restrict__ aacc_g,
    const float* __restrict__ topk_score,
    const int* __restrict__ topk_p, const int* __restrict__ endpos_p,
    float* __restrict__ rowloss)
{
    const int q   = blockIdx.x;
    const int tid = threadIdx.x;
    int K = min(topk_p[0], endpos_p[0]);
    K = min(K, KSEL);
    const int n = min(q + 1, K);

    __shared__ float sc[KSEL];
    __shared__ float aacc[KSEL];
    __shared__ float tmp[4];

    for (int j = tid; j < n; j += 256) aacc[j] = aacc_g[(size_t)q * KSEL + j];

    float tmaxl = -INFINITY;
    for (int j = tid; j < n; j += 256) {
        float t = topk_score[q * KSEL + j];
        sc[j] = t;
        tmaxl = fmaxf(tmaxl, t);
    }
    const float tm = blockReduceMax(tmaxl, tmp);
    float tsum = 0.f;
    for (int j = tid; j < n; j += 256) {
        float e = __expf(sc[j] - tm);
        sc[j] = e;
        tsum += e;
    }
    tsum = blockReduceSum(tsum, tmp);
    const float tinv = 1.f / tsum;

    float sa = 0.f;
    for (int j = tid; j < n; j += 256) sa += fabsf(aacc[j]);
    sa = blockReduceSum(sa, tmp);
    const float denom = fmaxf(sa, 1e-12f);

    float kl = 0.f;
    for (int j = tid; j < n; j += 256) {
        float tgt = aacc[j] / denom + 1e-8f;
        float pd  = sc[j] * tinv + 1e-8f;
        kl += tgt * (__logf(tgt) - __logf(pd));
    }
    kl = blockReduceSum(kl, tmp);
    if (tid == 0) rowloss[q] = kl;
}

// ---------------- Kernel C: loss = mean over rows ----------------
__global__ __launch_bounds__(256) void reduce_loss(const float* __restrict__ rowloss,
                                                   float* __restrict__ out) {
    __shared__ float tmp[4];
    float v = 0.f;
    for (int i = threadIdx.x; i < S; i += 256) v += rowloss[i];
    v = blockReduceSum(v, tmp);
    if (threadIdx.x == 0) out[0] = v / (float)S;
}

extern "C" void kernel_launch(void* const* d_in, const int* in_sizes, int n_in,
                              void* d_out, int out_size, void* d_ws, size_t ws_size,
                              hipStream_t stream) {
    const float* q   = (const float*)d_in[0];
    const float* k   = (const float*)d_in[1];
    const float* v   = (const float*)d_in[2];
    const float* qi  = (const float*)d_in[3];
    const float* ki  = (const float*)d_in[4];
    const float* w   = (const float*)d_in[5];
    const int* topk  = (const int*)d_in[6];
    const int* endp  = (const int*)d_in[7];
    float* out = (float*)d_out;

    char* ws = (char*)d_ws;
    const size_t MB = 1ull << 20;
    int*   topk_idx   = (int*)ws;                             // 4 MB
    float* topk_score = (float*)(ws + 4 * MB);                // 4 MB
    float* aacc_g     = (float*)(ws + 8 * MB);                // 4 MB
    float* rowloss    = (float*)(ws + 12 * MB);               // 64 KB
    char*  pbuf       = ws + 12 * MB + 65536;
    unsigned short* Kh  = (unsigned short*)pbuf;                    // 8 MB f16
    unsigned char*  Vq  = (unsigned char*)(pbuf + 8 * MB);          // 4 MB fp8
    unsigned short* qih = (unsigned short*)(pbuf + 12 * MB);        // 8 MB
    unsigned short* qil = (unsigned short*)(pbuf + 20 * MB);        // 8 MB
    unsigned short* kih = (unsigned short*)(pbuf + 28 * MB);        // 512 KB
    unsigned short* kil = (unsigned short*)(pbuf + 28 * MB + 512 * 1024); // 512 KB
    const size_t need_attn = 12 * MB + 65536 + 12 * MB;
    const size_t need_idx  = 12 * MB + 65536 + 29 * MB;

    if (ws_size >= need_idx && ws_size >= need_attn) {
        // fused fast path: one prep kernel (splits + converts + aacc zero)
        hipLaunchKernelGGL(prep_all, dim3(2048), dim3(256), 0, stream,
                           k, v, Kh, (unsigned int*)Vq,
                           qi, qih, qil, ki, kih, kil, aacc_g,
                           HQ * S * D / 4, S * HI * DI / 4, S * DI / 4,
                           S * KSEL / 4);
        hipLaunchKernelGGL(indexer_mfma, dim3(S / 2), dim3(256), 0, stream,
                           qih, qil, kih, kil, w, topk, endp, topk_idx, topk_score);
        hipLaunchKernelGGL(sparse_attn_v8, dim3(S, HQ), dim3(256), 0, stream,
                           q, Kh, Vq, topk_idx, topk, endp, out + 1, aacc_g);
    } else {
        hipLaunchKernelGGL(indexer_topk, dim3(S), dim3(256), 0, stream,
                           qi, ki, w, topk, endp, topk_idx, topk_score);
        hipMemsetAsync(aacc_g, 0, (size_t)S * KSEL * sizeof(float), stream);
        hipLaunchKernelGGL(sparse_attn2, dim3(S, HQ), dim3(256), 0, stream,
                           q, k, v, topk_idx, topk, endp, out + 1, aacc_g);
    }

    hipLaunchKernelGGL(row_loss, dim3(S), dim3(256), 0, stream,
                       aacc_g, topk_score, topk, endp, rowloss);
    hipLaunchKernelGGL(reduce_loss, dim3(1), dim3(256), 0, stream,
                       rowloss, out);
}